// Round 14
// baseline (411.762 us; speedup 1.0000x reference)
//
#include <hip/hip_runtime.h>

// GCN 3-layer: N=100000 nodes, E=1600000 edges, dims 20->64->48->32.
// CSR-by-dst via two-level bucket sort (no global atomics; EC=4096 so
// hist/bin use 391 blocks = full CU coverage). All feature streams bf16
// (fp32 accumulation), sequential node order. Aggregate edge loops are the
// R10 shape exactly (prologue + int4-indexed 16-wide + 4/1 tails): R11
// degree-sort, R12 masked-everywhere, R13 masked-tail all regressed it —
// this shape is the measured local optimum (low VGPR, compiler pipelines
// the 16-wide body). Layer 1 fused aggregate+GEMM+stats; layers 2/3
// GEMM-first; BN finalize inlined into consumers (8 stat buckets).

#define NN 100000
#define NE 1600000
constexpr float BN_EPS_F = 1e-5f;
constexpr float INVN = 1.f / (float)NN;

#define BSZ 128                       // nodes per bucket (power of 2)
#define NBKT ((NN + BSZ - 1) / BSZ)   // 782
#define EC 4096                       // edges per hist/bin block (391 blocks)
#define NEB ((NE + EC - 1) / EC)      // 391
#define MTOT (NBKT * NEB)             // 305762 partial-hist entries
#define CAP 4096                      // max edges per bucket (mean 2047)
#define SCH 4096                      // scan chunk (16 elems/thread)

// ---------------- bf16 helpers (RTE) ----------------

__device__ __forceinline__ unsigned f2bf(float f) {
  union { float f; unsigned u; } v; v.f = f;
  return (v.u + 0x7fffu + ((v.u >> 16) & 1u)) >> 16;
}
__device__ __forceinline__ unsigned pack_bf2(float f0, float f1) {
  return f2bf(f0) | (f2bf(f1) << 16);
}
__device__ __forceinline__ float bf_lo(unsigned u) {
  union { unsigned u; float f; } v; v.u = u << 16; return v.f;
}
__device__ __forceinline__ float bf_hi(unsigned u) {
  union { unsigned u; float f; } v; v.u = u & 0xffff0000u; return v.f;
}

// ---------------- bucket sort: hist -> scan -> bin -> finalize ----------------

__global__ void hist_pass(const int* __restrict__ dst, int* __restrict__ ph, int e) {
  __shared__ int h[NBKT];
  int tid = threadIdx.x;
  for (int i = tid; i < NBKT; i += 256) h[i] = 0;
  __syncthreads();
  int tbase = blockIdx.x * EC + tid * 16;
#pragma unroll
  for (int k = 0; k < 16; k += 4) {
    int i = tbase + k;
    if (i < e) {  // i%4==0 && e%4==0 -> whole quad in bounds
      int4 d = *(const int4*)(dst + i);
      atomicAdd(&h[d.x >> 7], 1);
      atomicAdd(&h[d.y >> 7], 1);
      atomicAdd(&h[d.z >> 7], 1);
      atomicAdd(&h[d.w >> 7], 1);
    }
  }
  __syncthreads();
  for (int i = tid; i < NBKT; i += 256) ph[i * NEB + blockIdx.x] = h[i];
}

// chunk = 4096 elems/block, 16/thread (thread-contiguous for scan_apply)
__global__ void scan_block_sums(const int* __restrict__ data, int* __restrict__ bsums, int n) {
  __shared__ int sd[256];
  int tid = threadIdx.x;
  int base = blockIdx.x * SCH + tid * 16;
  int s = 0;
#pragma unroll
  for (int j = 0; j < 16; j++) {
    int idx = base + j;
    if (idx < n) s += data[idx];
  }
  sd[tid] = s;
  __syncthreads();
  for (int o = 128; o > 0; o >>= 1) {
    if (tid < o) sd[tid] += sd[tid + o];
    __syncthreads();
  }
  if (tid == 0) bsums[blockIdx.x] = sd[0];
}

__global__ void scan_bsums2(int* __restrict__ bsums, int nb) {
  __shared__ int sd[128];
  int tid = threadIdx.x;
  int v = (tid < nb) ? bsums[tid] : 0;
  sd[tid] = v;
  __syncthreads();
  for (int o = 1; o < 128; o <<= 1) {
    int t = (tid >= o) ? sd[tid - o] : 0;
    __syncthreads();
    sd[tid] += t;
    __syncthreads();
  }
  if (tid < nb) bsums[tid] = sd[tid] - v;  // exclusive
}

__global__ void scan_apply(int* __restrict__ data, const int* __restrict__ bsums, int n) {
  __shared__ int sd[256];
  int tid = threadIdx.x;
  int base = blockIdx.x * SCH + tid * 16;
  int c[16];
  int s = 0;
#pragma unroll
  for (int j = 0; j < 16; j++) {
    int idx = base + j;
    c[j] = (idx < n) ? data[idx] : 0;
    s += c[j];
  }
  sd[tid] = s;
  __syncthreads();
  for (int o = 1; o < 256; o <<= 1) {
    int t = (tid >= o) ? sd[tid - o] : 0;
    __syncthreads();
    sd[tid] += t;
    __syncthreads();
  }
  int off = bsums[blockIdx.x] + sd[tid] - s;
#pragma unroll
  for (int j = 0; j < 16; j++) {
    int idx = base + j;
    if (idx < n) {
      data[idx] = off;
      off += c[j];
    }
  }
}

__global__ void bin_pass(const int* __restrict__ src, const int* __restrict__ dst,
                         const int* __restrict__ ph, int* __restrict__ packed, int e) {
  __shared__ int cur[NBKT];
  int tid = threadIdx.x;
  for (int i = tid; i < NBKT; i += 256) cur[i] = ph[i * NEB + blockIdx.x];
  __syncthreads();
  int tbase = blockIdx.x * EC + tid * 16;
#pragma unroll
  for (int k = 0; k < 16; k += 4) {
    int i = tbase + k;
    if (i < e) {
      int4 s = *(const int4*)(src + i);
      int4 d = *(const int4*)(dst + i);
      int p0 = atomicAdd(&cur[d.x >> 7], 1);
      int p1 = atomicAdd(&cur[d.y >> 7], 1);
      int p2 = atomicAdd(&cur[d.z >> 7], 1);
      int p3 = atomicAdd(&cur[d.w >> 7], 1);
      packed[p0] = (s.x << 7) | (d.x & 127);
      packed[p1] = (s.y << 7) | (d.y & 127);
      packed[p2] = (s.z << 7) | (d.z & 127);
      packed[p3] = (s.w << 7) | (d.w & 127);
    }
  }
}

// one block per bucket: emit dinv, rowptr, csr_src, and xb (pre-scaled bf16 x)
__global__ void bucket_finalize(const int* __restrict__ ph, const int* __restrict__ packed,
                                const float* __restrict__ x, int* __restrict__ rowptr,
                                float* __restrict__ dinv, int* __restrict__ csr_src,
                                unsigned* __restrict__ xb) {
  __shared__ int eidx[CAP];
  __shared__ int csr_l[CAP];
  __shared__ int ldeg[BSZ], lscan[BSZ], lcur[BSZ];
  __shared__ float ldinv[BSZ];
  int b = blockIdx.x, tid = threadIdx.x;
  int start = ph[b * NEB];
  int end = (b == NBKT - 1) ? NE : ph[(b + 1) * NEB];
  int cnt = end - start;
  if (cnt > CAP) cnt = CAP;  // statistically unreachable
  for (int i = tid; i < cnt; i += 256) eidx[i] = packed[start + i];
  if (tid < BSZ) ldeg[tid] = 0;
  __syncthreads();
  for (int i = tid; i < cnt; i += 256) atomicAdd(&ldeg[eidx[i] & 127], 1);
  __syncthreads();
  if (tid < BSZ) lscan[tid] = ldeg[tid];
  __syncthreads();
  for (int o = 1; o < BSZ; o <<= 1) {
    int t = 0;
    if (tid < BSZ && tid >= o) t = lscan[tid - o];
    __syncthreads();
    if (tid < BSZ) lscan[tid] += t;
    __syncthreads();
  }
  int gn = b * BSZ + tid;
  if (tid < BSZ) {
    int ex = lscan[tid] - ldeg[tid];  // exclusive
    lcur[tid] = ex;
    float dv = rsqrtf((float)(ldeg[tid] + 1));  // +1 self loop
    ldinv[tid] = dv;
    if (gn < NN) {
      rowptr[gn] = start + ex;
      dinv[gn] = dv;
    }
  }
  if (b == NBKT - 1 && tid == 0) rowptr[NN] = NE;
  __syncthreads();
  for (int i = tid; i < cnt; i += 256) {
    int pe = eidx[i];
    int pos = atomicAdd(&lcur[pe & 127], 1);
    csr_l[pos] = pe >> 7;
  }
  __syncthreads();
  for (int i = tid; i < cnt; i += 256) csr_src[start + i] = csr_l[i];
  // xb: rows of 16 uints (10 real = 20 channels), pre-scaled by dinv
  for (int i = tid; i < BSZ * 16; i += 256) {
    int nl = i >> 4, j = i & 15;
    int g2 = b * BSZ + nl;
    if (g2 < NN) {
      unsigned u = 0;
      if (j < 10) {
        float2 f = *(const float2*)(x + (size_t)g2 * 20 + 2 * j);
        float dd = ldinv[nl];
        u = pack_bf2(dd * f.x, dd * f.y);
      }
      xb[(size_t)g2 * 16 + j] = u;
    }
  }
}

// ---------------- layer 1 fused: aggregate x (bf16 gather) + 20x64 GEMM + BN1 stats ----------------
// 16 lanes/node, 16 nodes/block, sequential order. R10 loop shape.

__launch_bounds__(256)
__global__ void agg1_gemm1(const unsigned* __restrict__ mb, const int* __restrict__ rowptr,
                           const int* __restrict__ csr_src, const float* __restrict__ dinv,
                           const float* __restrict__ W1, const float* __restrict__ b1,
                           unsigned* __restrict__ h1u, float* __restrict__ gsum) {
  __shared__ float Wl[20 * 64];   // 5 KB
  __shared__ float Hl[16][20];    // 1.25 KB
  __shared__ float4 sbuf[256];    // 4 KB (two-phase: sums then squares)
  int tid = threadIdx.x;
  for (int i = tid; i < 20 * 64; i += 256) Wl[i] = W1[i];
  int sub = tid >> 4, lane = tid & 15;
  int cl = (lane < 10) ? lane : lane - 10;
  int d = blockIdx.x * 16 + sub;
  int start = rowptr[d], end = rowptr[d + 1];
  unsigned su = mb[(size_t)d * 16 + cl];
  float acc0 = bf_lo(su), acc1 = bf_hi(su);
  int j = start;
  int aligned = (start + 3) & ~3;
  int pe = aligned < end ? aligned : end;
  for (; j < pe; j++) {
    unsigned u = mb[(size_t)csr_src[j] * 16 + cl];
    acc0 += bf_lo(u); acc1 += bf_hi(u);
  }
  for (; j + 16 <= end; j += 16) {
    int4 s0 = *(const int4*)(csr_src + j);
    int4 s1 = *(const int4*)(csr_src + j + 4);
    int4 s2 = *(const int4*)(csr_src + j + 8);
    int4 s3 = *(const int4*)(csr_src + j + 12);
    int idx[16] = {s0.x, s0.y, s0.z, s0.w, s1.x, s1.y, s1.z, s1.w,
                   s2.x, s2.y, s2.z, s2.w, s3.x, s3.y, s3.z, s3.w};
    unsigned u[16];
#pragma unroll
    for (int t = 0; t < 16; t++) u[t] = mb[(size_t)idx[t] * 16 + cl];
#pragma unroll
    for (int t = 0; t < 16; t++) { acc0 += bf_lo(u[t]); acc1 += bf_hi(u[t]); }
  }
  for (; j + 4 <= end; j += 4) {
    int4 s0 = *(const int4*)(csr_src + j);
    unsigned u0 = mb[(size_t)s0.x * 16 + cl], u1 = mb[(size_t)s0.y * 16 + cl];
    unsigned u2 = mb[(size_t)s0.z * 16 + cl], u3 = mb[(size_t)s0.w * 16 + cl];
    acc0 += bf_lo(u0) + bf_lo(u1) + bf_lo(u2) + bf_lo(u3);
    acc1 += bf_hi(u0) + bf_hi(u1) + bf_hi(u2) + bf_hi(u3);
  }
  for (; j < end; j++) {
    unsigned u = mb[(size_t)csr_src[j] * 16 + cl];
    acc0 += bf_lo(u); acc1 += bf_hi(u);
  }
  float dd = dinv[d];
  if (lane < 10) {
    Hl[sub][2 * cl] = dd * acc0;
    Hl[sub][2 * cl + 1] = dd * acc1;
  }
  __syncthreads();
  // GEMM: thread (sub,lane) -> node sub, channels 4*lane..4*lane+3
  int cg = lane;
  float a0 = b1[4 * cg], a1 = b1[4 * cg + 1], a2 = b1[4 * cg + 2], a3 = b1[4 * cg + 3];
#pragma unroll
  for (int k = 0; k < 20; k++) {
    float a = Hl[sub][k];
    const float* w = &Wl[k * 64 + 4 * cg];
    a0 = fmaf(a, w[0], a0);
    a1 = fmaf(a, w[1], a1);
    a2 = fmaf(a, w[2], a2);
    a3 = fmaf(a, w[3], a3);
  }
  *(uint2*)(h1u + (size_t)d * 32 + 2 * cg) = make_uint2(pack_bf2(a0, a1), pack_bf2(a2, a3));
  // stats, two-phase through sbuf
  sbuf[tid] = make_float4(a0, a1, a2, a3);
  __syncthreads();
  float* gs = gsum + (blockIdx.x & 7) * 128;
  if (tid < 16) {
    float s0 = 0.f, s1 = 0.f, s2 = 0.f, s3 = 0.f;
#pragma unroll
    for (int k = 0; k < 16; k++) {
      float4 a = sbuf[k * 16 + tid];
      s0 += a.x; s1 += a.y; s2 += a.z; s3 += a.w;
    }
    atomicAdd(&gs[4 * tid], s0);
    atomicAdd(&gs[4 * tid + 1], s1);
    atomicAdd(&gs[4 * tid + 2], s2);
    atomicAdd(&gs[4 * tid + 3], s3);
  }
  __syncthreads();
  sbuf[tid] = make_float4(a0 * a0, a1 * a1, a2 * a2, a3 * a3);
  __syncthreads();
  if (tid < 16) {
    float q0 = 0.f, q1 = 0.f, q2 = 0.f, q3 = 0.f;
#pragma unroll
    for (int k = 0; k < 16; k++) {
      float4 b = sbuf[k * 16 + tid];
      q0 += b.x; q1 += b.y; q2 += b.z; q3 += b.w;
    }
    atomicAdd(&gs[64 + 4 * tid], q0);
    atomicAdd(&gs[64 + 4 * tid + 1], q1);
    atomicAdd(&gs[64 + 4 * tid + 2], q2);
    atomicAdd(&gs[64 + 4 * tid + 3], q3);
  }
}

// ---------------- layer-2 GEMM (inline BN1 finalize): h1 bf16 -> m2b bf16 24u pre-scaled ----------------

__launch_bounds__(256)
__global__ void gemm2_bf(const unsigned* __restrict__ hu, const float* __restrict__ W,
                         const float* __restrict__ gsum, const float* __restrict__ g,
                         const float* __restrict__ beta, const float* __restrict__ dinv,
                         unsigned* __restrict__ out) {
  __shared__ float Wl[64 * 48];
  __shared__ float Hl[16][64];
  __shared__ float scl[64], sft[64];
  int tid = threadIdx.x;
  int row0 = blockIdx.x * 16;
  if (tid < 64) {  // inline bn_finalize layer 1 (8 buckets)
    float s = 0.f, q = 0.f;
    for (int b = 0; b < 8; b++) {
      s += gsum[b * 128 + tid];
      q += gsum[b * 128 + 64 + tid];
    }
    float mean = s * INVN;
    float var = fmaxf(q * INVN - mean * mean, 0.f);
    float inv = rsqrtf(var + BN_EPS_F);
    float sc = g[tid] * inv;
    scl[tid] = sc;
    sft[tid] = beta[tid] - mean * sc;
  }
  for (int i = tid; i < 64 * 48; i += 256) Wl[i] = W[i];
  __syncthreads();
  for (int i = tid; i < 16 * 32; i += 256) {
    int r = i >> 5, j = i & 31;
    unsigned u = hu[(size_t)(row0 + r) * 32 + j];
    Hl[r][2 * j] = fmaxf(fmaf(bf_lo(u), scl[2 * j], sft[2 * j]), 0.f);
    Hl[r][2 * j + 1] = fmaxf(fmaf(bf_hi(u), scl[2 * j + 1], sft[2 * j + 1]), 0.f);
  }
  __syncthreads();
  int r = tid >> 4, c = tid & 15;
  if (c < 12) {
    float a0 = 0.f, a1 = 0.f, a2 = 0.f, a3 = 0.f;
#pragma unroll
    for (int k = 0; k < 64; k++) {
      float a = Hl[r][k];
      const float* w = &Wl[k * 48 + 4 * c];
      a0 = fmaf(a, w[0], a0);
      a1 = fmaf(a, w[1], a1);
      a2 = fmaf(a, w[2], a2);
      a3 = fmaf(a, w[3], a3);
    }
    float dd = dinv[row0 + r];
    uint2 uo = make_uint2(pack_bf2(dd * a0, dd * a1), pack_bf2(dd * a2, dd * a3));
    *(uint2*)(out + (size_t)(row0 + r) * 24 + 2 * c) = uo;
  }
}

// ---------------- layer-2 aggregate: bf16 rows of 24 uints (96B) -> bf16 h2 (24u), BN2 stats ----------------
// R10 loop shape.

__launch_bounds__(256)
__global__ void aggregate_bf48(const uint2* __restrict__ mb, const int* __restrict__ rowptr,
                               const int* __restrict__ csr_src, const float* __restrict__ dinv,
                               const float* __restrict__ bias, unsigned* __restrict__ out,
                               float* __restrict__ gsum) {
  __shared__ float4 sbuf[256];  // 4 KB, two-phase
  int tid = threadIdx.x;
  int sub = tid >> 4, lane = tid & 15;
  int cl = (lane < 12) ? lane : lane - 12;
  int d = blockIdx.x * 16 + sub;
  int start = rowptr[d], end = rowptr[d + 1];
  uint2 su = mb[(size_t)d * 12 + cl];
  float acc0 = bf_lo(su.x), acc1 = bf_hi(su.x), acc2 = bf_lo(su.y), acc3 = bf_hi(su.y);
  int j = start;
  int aligned = (start + 3) & ~3;
  int pe = aligned < end ? aligned : end;
  for (; j < pe; j++) {
    uint2 u = mb[(size_t)csr_src[j] * 12 + cl];
    acc0 += bf_lo(u.x); acc1 += bf_hi(u.x); acc2 += bf_lo(u.y); acc3 += bf_hi(u.y);
  }
  for (; j + 16 <= end; j += 16) {
    int4 s0 = *(const int4*)(csr_src + j);
    int4 s1 = *(const int4*)(csr_src + j + 4);
    int4 s2 = *(const int4*)(csr_src + j + 8);
    int4 s3 = *(const int4*)(csr_src + j + 12);
    int idx[16] = {s0.x, s0.y, s0.z, s0.w, s1.x, s1.y, s1.z, s1.w,
                   s2.x, s2.y, s2.z, s2.w, s3.x, s3.y, s3.z, s3.w};
    uint2 u[16];
#pragma unroll
    for (int t = 0; t < 16; t++) u[t] = mb[(size_t)idx[t] * 12 + cl];
#pragma unroll
    for (int t = 0; t < 16; t++) {
      acc0 += bf_lo(u[t].x); acc1 += bf_hi(u[t].x);
      acc2 += bf_lo(u[t].y); acc3 += bf_hi(u[t].y);
    }
  }
  for (; j + 4 <= end; j += 4) {
    int4 s0 = *(const int4*)(csr_src + j);
    uint2 u0 = mb[(size_t)s0.x * 12 + cl], u1 = mb[(size_t)s0.y * 12 + cl];
    uint2 u2 = mb[(size_t)s0.z * 12 + cl], u3 = mb[(size_t)s0.w * 12 + cl];
    acc0 += bf_lo(u0.x) + bf_lo(u1.x) + bf_lo(u2.x) + bf_lo(u3.x);
    acc1 += bf_hi(u0.x) + bf_hi(u1.x) + bf_hi(u2.x) + bf_hi(u3.x);
    acc2 += bf_lo(u0.y) + bf_lo(u1.y) + bf_lo(u2.y) + bf_lo(u3.y);
    acc3 += bf_hi(u0.y) + bf_hi(u1.y) + bf_hi(u2.y) + bf_hi(u3.y);
  }
  for (; j < end; j++) {
    uint2 u = mb[(size_t)csr_src[j] * 12 + cl];
    acc0 += bf_lo(u.x); acc1 += bf_hi(u.x); acc2 += bf_lo(u.y); acc3 += bf_hi(u.y);
  }
  float dd = dinv[d];
  float v0 = dd * acc0 + bias[4 * cl];
  float v1 = dd * acc1 + bias[4 * cl + 1];
  float v2 = dd * acc2 + bias[4 * cl + 2];
  float v3 = dd * acc3 + bias[4 * cl + 3];
  if (lane >= 12) { v0 = v1 = v2 = v3 = 0.f; }
  if (lane < 12) {
    uint2 uo = make_uint2(pack_bf2(v0, v1), pack_bf2(v2, v3));
    *(uint2*)(out + (size_t)d * 24 + 2 * cl) = uo;
  }
  sbuf[tid] = make_float4(v0, v1, v2, v3);
  __syncthreads();
  float* gs = gsum + (blockIdx.x & 7) * 128;
  if (tid < 12) {
    float s0 = 0.f, s1 = 0.f, s2 = 0.f, s3 = 0.f;
#pragma unroll
    for (int k = 0; k < 16; k++) {
      float4 a = sbuf[k * 16 + tid];
      s0 += a.x; s1 += a.y; s2 += a.z; s3 += a.w;
    }
    atomicAdd(&gs[4 * tid], s0);
    atomicAdd(&gs[4 * tid + 1], s1);
    atomicAdd(&gs[4 * tid + 2], s2);
    atomicAdd(&gs[4 * tid + 3], s3);
  }
  __syncthreads();
  sbuf[tid] = make_float4(v0 * v0, v1 * v1, v2 * v2, v3 * v3);
  __syncthreads();
  if (tid < 12) {
    float q0 = 0.f, q1 = 0.f, q2 = 0.f, q3 = 0.f;
#pragma unroll
    for (int k = 0; k < 16; k++) {
      float4 b = sbuf[k * 16 + tid];
      q0 += b.x; q1 += b.y; q2 += b.z; q3 += b.w;
    }
    atomicAdd(&gs[64 + 4 * tid], q0);
    atomicAdd(&gs[64 + 4 * tid + 1], q1);
    atomicAdd(&gs[64 + 4 * tid + 2], q2);
    atomicAdd(&gs[64 + 4 * tid + 3], q3);
  }
}

// ---------------- layer-3 GEMM (inline BN2 finalize): h2 bf16 24u -> m3b bf16 16u pre-scaled ----------------

__launch_bounds__(256)
__global__ void gemm3_bf(const unsigned* __restrict__ hu, const float* __restrict__ W,
                         const float* __restrict__ gsum, const float* __restrict__ g,
                         const float* __restrict__ beta, const float* __restrict__ dinv,
                         unsigned* __restrict__ out) {
  __shared__ float Wl[48 * 32];
  __shared__ float Hl[16][48];
  __shared__ float scl[48], sft[48];
  int tid = threadIdx.x;
  int row0 = blockIdx.x * 16;
  if (tid < 48) {  // inline bn_finalize layer 2 (8 buckets)
    float s = 0.f, q = 0.f;
    for (int b = 0; b < 8; b++) {
      s += gsum[b * 128 + tid];
      q += gsum[b * 128 + 64 + tid];
    }
    float mean = s * INVN;
    float var = fmaxf(q * INVN - mean * mean, 0.f);
    float inv = rsqrtf(var + BN_EPS_F);
    float sc = g[tid] * inv;
    scl[tid] = sc;
    sft[tid] = beta[tid] - mean * sc;
  }
  for (int i = tid; i < 48 * 32; i += 256) Wl[i] = W[i];
  __syncthreads();
  for (int i = tid; i < 16 * 24; i += 256) {
    int r = i / 24, j = i % 24;
    unsigned u = hu[(size_t)(row0 + r) * 24 + j];
    Hl[r][2 * j] = fmaxf(fmaf(bf_lo(u), scl[2 * j], sft[2 * j]), 0.f);
    Hl[r][2 * j + 1] = fmaxf(fmaf(bf_hi(u), scl[2 * j + 1], sft[2 * j + 1]), 0.f);
  }
  __syncthreads();
  int r = tid >> 4, c2 = tid & 15;
  float a0 = 0.f, a1 = 0.f;
#pragma unroll
  for (int k = 0; k < 48; k++) {
    float a = Hl[r][k];
    a0 = fmaf(a, Wl[k * 32 + 2 * c2], a0);
    a1 = fmaf(a, Wl[k * 32 + 2 * c2 + 1], a1);
  }
  float dd = dinv[row0 + r];
  out[(size_t)(row0 + r) * 16 + c2] = pack_bf2(dd * a0, dd * a1);
}

// ---------------- layer-3 aggregate: bf16 rows 16u -> bf16 h3 16u, BN3 stats ----------------
// R10 loop shape.

__launch_bounds__(256)
__global__ void aggregate_bf32(const unsigned* __restrict__ mb, const int* __restrict__ rowptr,
                               const int* __restrict__ csr_src, const float* __restrict__ dinv,
                               const float* __restrict__ bias, unsigned* __restrict__ out,
                               float* __restrict__ gsum) {
  __shared__ float2 ssum[256], ssq[256];
  int tid = threadIdx.x;
  int sub = tid >> 4, lane = tid & 15;
  int d = blockIdx.x * 16 + sub;
  int start = rowptr[d], end = rowptr[d + 1];
  unsigned su = mb[(size_t)d * 16 + lane];
  float acc0 = bf_lo(su), acc1 = bf_hi(su);
  int j = start;
  int aligned = (start + 3) & ~3;
  int pe = aligned < end ? aligned : end;
  for (; j < pe; j++) {
    unsigned u = mb[(size_t)csr_src[j] * 16 + lane];
    acc0 += bf_lo(u); acc1 += bf_hi(u);
  }
  for (; j + 16 <= end; j += 16) {
    int4 s0 = *(const int4*)(csr_src + j);
    int4 s1 = *(const int4*)(csr_src + j + 4);
    int4 s2 = *(const int4*)(csr_src + j + 8);
    int4 s3 = *(const int4*)(csr_src + j + 12);
    int idx[16] = {s0.x, s0.y, s0.z, s0.w, s1.x, s1.y, s1.z, s1.w,
                   s2.x, s2.y, s2.z, s2.w, s3.x, s3.y, s3.z, s3.w};
    unsigned u[16];
#pragma unroll
    for (int t = 0; t < 16; t++) u[t] = mb[(size_t)idx[t] * 16 + lane];
#pragma unroll
    for (int t = 0; t < 16; t++) { acc0 += bf_lo(u[t]); acc1 += bf_hi(u[t]); }
  }
  for (; j + 4 <= end; j += 4) {
    int4 s0 = *(const int4*)(csr_src + j);
    unsigned u0 = mb[(size_t)s0.x * 16 + lane], u1 = mb[(size_t)s0.y * 16 + lane];
    unsigned u2 = mb[(size_t)s0.z * 16 + lane], u3 = mb[(size_t)s0.w * 16 + lane];
    acc0 += bf_lo(u0) + bf_lo(u1) + bf_lo(u2) + bf_lo(u3);
    acc1 += bf_hi(u0) + bf_hi(u1) + bf_hi(u2) + bf_hi(u3);
  }
  for (; j < end; j++) {
    unsigned u = mb[(size_t)csr_src[j] * 16 + lane];
    acc0 += bf_lo(u); acc1 += bf_hi(u);
  }
  float dd = dinv[d];
  float v0 = dd * acc0 + bias[2 * lane];
  float v1 = dd * acc1 + bias[2 * lane + 1];
  out[(size_t)d * 16 + lane] = pack_bf2(v0, v1);
  ssum[tid] = make_float2(v0, v1);
  ssq[tid] = make_float2(v0 * v0, v1 * v1);
  __syncthreads();
  if (tid < 16) {
    float s0 = 0.f, s1 = 0.f, q0 = 0.f, q1 = 0.f;
#pragma unroll
    for (int k = 0; k < 16; k++) {
      float2 a = ssum[k * 16 + tid];
      float2 b = ssq[k * 16 + tid];
      s0 += a.x; s1 += a.y; q0 += b.x; q1 += b.y;
    }
    float* gs = gsum + (blockIdx.x & 7) * 128;
    atomicAdd(&gs[2 * tid], s0);
    atomicAdd(&gs[2 * tid + 1], s1);
    atomicAdd(&gs[64 + 2 * tid], q0);
    atomicAdd(&gs[64 + 2 * tid + 1], q1);
  }
}

// ---------------- BN3 finalize (inline) + apply: bf16 h3 -> fp32 out ----------------

__launch_bounds__(256)
__global__ void bn_apply_out(const unsigned* __restrict__ hu, const float* __restrict__ gsum,
                             const float* __restrict__ g, const float* __restrict__ beta,
                             float* __restrict__ out) {
  __shared__ float scl[32], sft[32];
  int tid = threadIdx.x;
  if (tid < 32) {  // inline bn_finalize layer 3 (8 buckets)
    float s = 0.f, q = 0.f;
    for (int b = 0; b < 8; b++) {
      s += gsum[b * 128 + tid];
      q += gsum[b * 128 + 64 + tid];
    }
    float mean = s * INVN;
    float var = fmaxf(q * INVN - mean * mean, 0.f);
    float inv = rsqrtf(var + BN_EPS_F);
    float sc = g[tid] * inv;
    scl[tid] = sc;
    sft[tid] = beta[tid] - mean * sc;
  }
  __syncthreads();
  int base = (blockIdx.x * 256 + tid) * 4;  // 4 consecutive elems, same node
  int node = base >> 5;
  int c0 = base & 31;
  uint2 u = *(const uint2*)(hu + (size_t)node * 16 + (c0 >> 1));
  float4 o;
  o.x = bf_lo(u.x) * scl[c0] + sft[c0];
  o.y = bf_hi(u.x) * scl[c0 + 1] + sft[c0 + 1];
  o.z = bf_lo(u.y) * scl[c0 + 2] + sft[c0 + 2];
  o.w = bf_hi(u.y) * scl[c0 + 3] + sft[c0 + 3];
  *(float4*)(out + base) = o;
}

// ---------------- launch ----------------

extern "C" void kernel_launch(void* const* d_in, const int* in_sizes, int n_in,
                              void* d_out, int out_size, void* d_ws, size_t ws_size,
                              hipStream_t stream) {
  const float* x = (const float*)d_in[0];
  const int* ei = (const int*)d_in[1];
  const float* W1 = (const float*)d_in[2];
  const float* b1 = (const float*)d_in[3];
  const float* g1 = (const float*)d_in[4];
  const float* be1 = (const float*)d_in[5];
  const float* W2 = (const float*)d_in[6];
  const float* b2 = (const float*)d_in[7];
  const float* g2 = (const float*)d_in[8];
  const float* be2 = (const float*)d_in[9];
  const float* W3 = (const float*)d_in[10];
  const float* b3 = (const float*)d_in[11];
  const float* g3 = (const float*)d_in[12];
  const float* be3 = (const float*)d_in[13];
  float* out = (float*)d_out;

  const int* src = ei;
  const int* dst = ei + NE;

  char* ws = (char*)d_ws;
  size_t off = 0;
  auto alloc = [&](size_t bytes) -> void* {
    void* p = ws + off;
    off += bytes;
    off = (off + 255) & ~(size_t)255;
    return p;
  };
  int* ph = (int*)alloc((size_t)MTOT * 4);
  int* bsums = (int*)alloc(128 * 4);
  int* packed = (int*)alloc((size_t)NE * 4);
  int* rowptr = (int*)alloc((NN + 1) * 4);
  int* csr_src = (int*)alloc((size_t)NE * 4);
  float* dinv = (float*)alloc(NN * 4);
  float* gsum = (float*)alloc(3 * 8 * 128 * 4);
  unsigned* xb = (unsigned*)alloc((size_t)NN * 16 * 4);   // 6.4 MB (reused: m3b)
  unsigned* h1u = (unsigned*)alloc((size_t)NN * 32 * 4);  // 12.8 MB (reused: h3)
  unsigned* m2b = (unsigned*)alloc((size_t)NN * 24 * 4);  // 9.6 MB
  unsigned* h2u = (unsigned*)alloc((size_t)NN * 24 * 4);  // 9.6 MB

  unsigned* m3b = xb;   // xb dead after agg1_gemm1
  unsigned* h3u = h1u;  // h1 dead after gemm2

  hipMemsetAsync(gsum, 0, 3 * 8 * 128 * 4, stream);

  const int nscan = (MTOT + SCH - 1) / SCH;  // 75
  hist_pass<<<NEB, 256, 0, stream>>>(dst, ph, NE);
  scan_block_sums<<<nscan, 256, 0, stream>>>(ph, bsums, MTOT);
  scan_bsums2<<<1, 128, 0, stream>>>(bsums, nscan);
  scan_apply<<<nscan, 256, 0, stream>>>(ph, bsums, MTOT);
  bin_pass<<<NEB, 256, 0, stream>>>(src, dst, ph, packed, NE);
  bucket_finalize<<<NBKT, 256, 0, stream>>>(ph, packed, x, rowptr, dinv, csr_src, xb);

  // layer 1: fused aggregate(x) + GEMM1 + BN1 stats
  agg1_gemm1<<<NN / 16, 256, 0, stream>>>(xb, rowptr, csr_src, dinv, W1, b1, h1u, gsum);

  // layer 2: GEMM2 (inline BN1 finalize) -> aggregate (BN2 stats)
  gemm2_bf<<<NN / 16, 256, 0, stream>>>(h1u, W2, gsum, g1, be1, dinv, m2b);
  aggregate_bf48<<<NN / 16, 256, 0, stream>>>((const uint2*)m2b, rowptr, csr_src, dinv, b2, h2u,
                                              gsum + 1024);

  // layer 3: GEMM3 (inline BN2 finalize) -> aggregate (BN3 stats)
  gemm3_bf<<<NN / 16, 256, 0, stream>>>(h2u, W3, gsum + 1024, g2, be2, dinv, m3b);
  aggregate_bf32<<<NN / 16, 256, 0, stream>>>(m3b, rowptr, csr_src, dinv, b3, h3u, gsum + 2048);

  // BN3 finalize (inline) + apply
  bn_apply_out<<<NN * 32 / 1024, 256, 0, stream>>>(h3u, gsum + 2048, g3, be3, out);
}

// Round 15
// 333.631 us; speedup vs baseline: 1.2342x; 1.2342x over previous
//
#include <hip/hip_runtime.h>

// GCN 3-layer: N=100000 nodes, E=1600000 edges, dims 20->64->48->32.
// CSR-by-dst via two-level bucket sort (no global atomics; EC=4096 so
// hist/bin use 391 blocks = full CU coverage). All feature streams bf16
// (fp32 accumulation), sequential node order, R10 aggregate loop shape
// (prologue + int4-indexed 16-wide + 4/1 tails — all variants regressed).
// BN stats use 32 buckets: R11-R14's 8-bucket gsum caused ~780-way
// serialized atomic contention per address (~+50us per aggregate) and was
// the real cause of those regressions. Layer 1 fused aggregate+GEMM+stats;
// layers 2/3 GEMM-first; BN finalize inlined into consumers.

#define NN 100000
#define NE 1600000
constexpr float BN_EPS_F = 1e-5f;
constexpr float INVN = 1.f / (float)NN;

#define BSZ 128                       // nodes per bucket (power of 2)
#define NBKT ((NN + BSZ - 1) / BSZ)   // 782
#define EC 4096                       // edges per hist/bin block (391 blocks)
#define NEB ((NE + EC - 1) / EC)      // 391
#define MTOT (NBKT * NEB)             // 305762 partial-hist entries
#define CAP 4096                      // max edges per bucket (mean 2047)
#define SCH 4096                      // scan chunk (16 elems/thread)

// ---------------- bf16 helpers (RTE) ----------------

__device__ __forceinline__ unsigned f2bf(float f) {
  union { float f; unsigned u; } v; v.f = f;
  return (v.u + 0x7fffu + ((v.u >> 16) & 1u)) >> 16;
}
__device__ __forceinline__ unsigned pack_bf2(float f0, float f1) {
  return f2bf(f0) | (f2bf(f1) << 16);
}
__device__ __forceinline__ float bf_lo(unsigned u) {
  union { unsigned u; float f; } v; v.u = u << 16; return v.f;
}
__device__ __forceinline__ float bf_hi(unsigned u) {
  union { unsigned u; float f; } v; v.u = u & 0xffff0000u; return v.f;
}

// ---------------- bucket sort: hist -> scan -> bin -> finalize ----------------

__global__ void hist_pass(const int* __restrict__ dst, int* __restrict__ ph, int e) {
  __shared__ int h[NBKT];
  int tid = threadIdx.x;
  for (int i = tid; i < NBKT; i += 256) h[i] = 0;
  __syncthreads();
  int tbase = blockIdx.x * EC + tid * 16;
#pragma unroll
  for (int k = 0; k < 16; k += 4) {
    int i = tbase + k;
    if (i < e) {  // i%4==0 && e%4==0 -> whole quad in bounds
      int4 d = *(const int4*)(dst + i);
      atomicAdd(&h[d.x >> 7], 1);
      atomicAdd(&h[d.y >> 7], 1);
      atomicAdd(&h[d.z >> 7], 1);
      atomicAdd(&h[d.w >> 7], 1);
    }
  }
  __syncthreads();
  for (int i = tid; i < NBKT; i += 256) ph[i * NEB + blockIdx.x] = h[i];
}

// chunk = 4096 elems/block, 16/thread (thread-contiguous for scan_apply)
__global__ void scan_block_sums(const int* __restrict__ data, int* __restrict__ bsums, int n) {
  __shared__ int sd[256];
  int tid = threadIdx.x;
  int base = blockIdx.x * SCH + tid * 16;
  int s = 0;
#pragma unroll
  for (int j = 0; j < 16; j++) {
    int idx = base + j;
    if (idx < n) s += data[idx];
  }
  sd[tid] = s;
  __syncthreads();
  for (int o = 128; o > 0; o >>= 1) {
    if (tid < o) sd[tid] += sd[tid + o];
    __syncthreads();
  }
  if (tid == 0) bsums[blockIdx.x] = sd[0];
}

__global__ void scan_bsums2(int* __restrict__ bsums, int nb) {
  __shared__ int sd[128];
  int tid = threadIdx.x;
  int v = (tid < nb) ? bsums[tid] : 0;
  sd[tid] = v;
  __syncthreads();
  for (int o = 1; o < 128; o <<= 1) {
    int t = (tid >= o) ? sd[tid - o] : 0;
    __syncthreads();
    sd[tid] += t;
    __syncthreads();
  }
  if (tid < nb) bsums[tid] = sd[tid] - v;  // exclusive
}

__global__ void scan_apply(int* __restrict__ data, const int* __restrict__ bsums, int n) {
  __shared__ int sd[256];
  int tid = threadIdx.x;
  int base = blockIdx.x * SCH + tid * 16;
  int c[16];
  int s = 0;
#pragma unroll
  for (int j = 0; j < 16; j++) {
    int idx = base + j;
    c[j] = (idx < n) ? data[idx] : 0;
    s += c[j];
  }
  sd[tid] = s;
  __syncthreads();
  for (int o = 1; o < 256; o <<= 1) {
    int t = (tid >= o) ? sd[tid - o] : 0;
    __syncthreads();
    sd[tid] += t;
    __syncthreads();
  }
  int off = bsums[blockIdx.x] + sd[tid] - s;
#pragma unroll
  for (int j = 0; j < 16; j++) {
    int idx = base + j;
    if (idx < n) {
      data[idx] = off;
      off += c[j];
    }
  }
}

__global__ void bin_pass(const int* __restrict__ src, const int* __restrict__ dst,
                         const int* __restrict__ ph, int* __restrict__ packed, int e) {
  __shared__ int cur[NBKT];
  int tid = threadIdx.x;
  for (int i = tid; i < NBKT; i += 256) cur[i] = ph[i * NEB + blockIdx.x];
  __syncthreads();
  int tbase = blockIdx.x * EC + tid * 16;
#pragma unroll
  for (int k = 0; k < 16; k += 4) {
    int i = tbase + k;
    if (i < e) {
      int4 s = *(const int4*)(src + i);
      int4 d = *(const int4*)(dst + i);
      int p0 = atomicAdd(&cur[d.x >> 7], 1);
      int p1 = atomicAdd(&cur[d.y >> 7], 1);
      int p2 = atomicAdd(&cur[d.z >> 7], 1);
      int p3 = atomicAdd(&cur[d.w >> 7], 1);
      packed[p0] = (s.x << 7) | (d.x & 127);
      packed[p1] = (s.y << 7) | (d.y & 127);
      packed[p2] = (s.z << 7) | (d.z & 127);
      packed[p3] = (s.w << 7) | (d.w & 127);
    }
  }
}

// one block per bucket: emit dinv, rowptr, csr_src, and xb (pre-scaled bf16 x)
__global__ void bucket_finalize(const int* __restrict__ ph, const int* __restrict__ packed,
                                const float* __restrict__ x, int* __restrict__ rowptr,
                                float* __restrict__ dinv, int* __restrict__ csr_src,
                                unsigned* __restrict__ xb) {
  __shared__ int eidx[CAP];
  __shared__ int csr_l[CAP];
  __shared__ int ldeg[BSZ], lscan[BSZ], lcur[BSZ];
  __shared__ float ldinv[BSZ];
  int b = blockIdx.x, tid = threadIdx.x;
  int start = ph[b * NEB];
  int end = (b == NBKT - 1) ? NE : ph[(b + 1) * NEB];
  int cnt = end - start;
  if (cnt > CAP) cnt = CAP;  // statistically unreachable
  for (int i = tid; i < cnt; i += 256) eidx[i] = packed[start + i];
  if (tid < BSZ) ldeg[tid] = 0;
  __syncthreads();
  for (int i = tid; i < cnt; i += 256) atomicAdd(&ldeg[eidx[i] & 127], 1);
  __syncthreads();
  if (tid < BSZ) lscan[tid] = ldeg[tid];
  __syncthreads();
  for (int o = 1; o < BSZ; o <<= 1) {
    int t = 0;
    if (tid < BSZ && tid >= o) t = lscan[tid - o];
    __syncthreads();
    if (tid < BSZ) lscan[tid] += t;
    __syncthreads();
  }
  int gn = b * BSZ + tid;
  if (tid < BSZ) {
    int ex = lscan[tid] - ldeg[tid];  // exclusive
    lcur[tid] = ex;
    float dv = rsqrtf((float)(ldeg[tid] + 1));  // +1 self loop
    ldinv[tid] = dv;
    if (gn < NN) {
      rowptr[gn] = start + ex;
      dinv[gn] = dv;
    }
  }
  if (b == NBKT - 1 && tid == 0) rowptr[NN] = NE;
  __syncthreads();
  for (int i = tid; i < cnt; i += 256) {
    int pe = eidx[i];
    int pos = atomicAdd(&lcur[pe & 127], 1);
    csr_l[pos] = pe >> 7;
  }
  __syncthreads();
  for (int i = tid; i < cnt; i += 256) csr_src[start + i] = csr_l[i];
  // xb: rows of 16 uints (10 real = 20 channels), pre-scaled by dinv
  for (int i = tid; i < BSZ * 16; i += 256) {
    int nl = i >> 4, j = i & 15;
    int g2 = b * BSZ + nl;
    if (g2 < NN) {
      unsigned u = 0;
      if (j < 10) {
        float2 f = *(const float2*)(x + (size_t)g2 * 20 + 2 * j);
        float dd = ldinv[nl];
        u = pack_bf2(dd * f.x, dd * f.y);
      }
      xb[(size_t)g2 * 16 + j] = u;
    }
  }
}

// ---------------- layer 1 fused: aggregate x (bf16 gather) + 20x64 GEMM + BN1 stats ----------------
// 16 lanes/node, 16 nodes/block, sequential order. R10 loop shape, 32 stat buckets.

__launch_bounds__(256)
__global__ void agg1_gemm1(const unsigned* __restrict__ mb, const int* __restrict__ rowptr,
                           const int* __restrict__ csr_src, const float* __restrict__ dinv,
                           const float* __restrict__ W1, const float* __restrict__ b1,
                           unsigned* __restrict__ h1u, float* __restrict__ gsum) {
  __shared__ float Wl[20 * 64];   // 5 KB
  __shared__ float Hl[16][20];    // 1.25 KB
  __shared__ float4 sbuf[256];    // 4 KB (two-phase: sums then squares)
  int tid = threadIdx.x;
  for (int i = tid; i < 20 * 64; i += 256) Wl[i] = W1[i];
  int sub = tid >> 4, lane = tid & 15;
  int cl = (lane < 10) ? lane : lane - 10;
  int d = blockIdx.x * 16 + sub;
  int start = rowptr[d], end = rowptr[d + 1];
  unsigned su = mb[(size_t)d * 16 + cl];
  float acc0 = bf_lo(su), acc1 = bf_hi(su);
  int j = start;
  int aligned = (start + 3) & ~3;
  int pe = aligned < end ? aligned : end;
  for (; j < pe; j++) {
    unsigned u = mb[(size_t)csr_src[j] * 16 + cl];
    acc0 += bf_lo(u); acc1 += bf_hi(u);
  }
  for (; j + 16 <= end; j += 16) {
    int4 s0 = *(const int4*)(csr_src + j);
    int4 s1 = *(const int4*)(csr_src + j + 4);
    int4 s2 = *(const int4*)(csr_src + j + 8);
    int4 s3 = *(const int4*)(csr_src + j + 12);
    int idx[16] = {s0.x, s0.y, s0.z, s0.w, s1.x, s1.y, s1.z, s1.w,
                   s2.x, s2.y, s2.z, s2.w, s3.x, s3.y, s3.z, s3.w};
    unsigned u[16];
#pragma unroll
    for (int t = 0; t < 16; t++) u[t] = mb[(size_t)idx[t] * 16 + cl];
#pragma unroll
    for (int t = 0; t < 16; t++) { acc0 += bf_lo(u[t]); acc1 += bf_hi(u[t]); }
  }
  for (; j + 4 <= end; j += 4) {
    int4 s0 = *(const int4*)(csr_src + j);
    unsigned u0 = mb[(size_t)s0.x * 16 + cl], u1 = mb[(size_t)s0.y * 16 + cl];
    unsigned u2 = mb[(size_t)s0.z * 16 + cl], u3 = mb[(size_t)s0.w * 16 + cl];
    acc0 += bf_lo(u0) + bf_lo(u1) + bf_lo(u2) + bf_lo(u3);
    acc1 += bf_hi(u0) + bf_hi(u1) + bf_hi(u2) + bf_hi(u3);
  }
  for (; j < end; j++) {
    unsigned u = mb[(size_t)csr_src[j] * 16 + cl];
    acc0 += bf_lo(u); acc1 += bf_hi(u);
  }
  float dd = dinv[d];
  if (lane < 10) {
    Hl[sub][2 * cl] = dd * acc0;
    Hl[sub][2 * cl + 1] = dd * acc1;
  }
  __syncthreads();
  // GEMM: thread (sub,lane) -> node sub, channels 4*lane..4*lane+3
  int cg = lane;
  float a0 = b1[4 * cg], a1 = b1[4 * cg + 1], a2 = b1[4 * cg + 2], a3 = b1[4 * cg + 3];
#pragma unroll
  for (int k = 0; k < 20; k++) {
    float a = Hl[sub][k];
    const float* w = &Wl[k * 64 + 4 * cg];
    a0 = fmaf(a, w[0], a0);
    a1 = fmaf(a, w[1], a1);
    a2 = fmaf(a, w[2], a2);
    a3 = fmaf(a, w[3], a3);
  }
  *(uint2*)(h1u + (size_t)d * 32 + 2 * cg) = make_uint2(pack_bf2(a0, a1), pack_bf2(a2, a3));
  // stats, two-phase through sbuf
  sbuf[tid] = make_float4(a0, a1, a2, a3);
  __syncthreads();
  float* gs = gsum + (blockIdx.x & 31) * 128;
  if (tid < 16) {
    float s0 = 0.f, s1 = 0.f, s2 = 0.f, s3 = 0.f;
#pragma unroll
    for (int k = 0; k < 16; k++) {
      float4 a = sbuf[k * 16 + tid];
      s0 += a.x; s1 += a.y; s2 += a.z; s3 += a.w;
    }
    atomicAdd(&gs[4 * tid], s0);
    atomicAdd(&gs[4 * tid + 1], s1);
    atomicAdd(&gs[4 * tid + 2], s2);
    atomicAdd(&gs[4 * tid + 3], s3);
  }
  __syncthreads();
  sbuf[tid] = make_float4(a0 * a0, a1 * a1, a2 * a2, a3 * a3);
  __syncthreads();
  if (tid < 16) {
    float q0 = 0.f, q1 = 0.f, q2 = 0.f, q3 = 0.f;
#pragma unroll
    for (int k = 0; k < 16; k++) {
      float4 b = sbuf[k * 16 + tid];
      q0 += b.x; q1 += b.y; q2 += b.z; q3 += b.w;
    }
    atomicAdd(&gs[64 + 4 * tid], q0);
    atomicAdd(&gs[64 + 4 * tid + 1], q1);
    atomicAdd(&gs[64 + 4 * tid + 2], q2);
    atomicAdd(&gs[64 + 4 * tid + 3], q3);
  }
}

// ---------------- layer-2 GEMM (inline BN1 finalize): h1 bf16 -> m2b bf16 24u pre-scaled ----------------

__launch_bounds__(256)
__global__ void gemm2_bf(const unsigned* __restrict__ hu, const float* __restrict__ W,
                         const float* __restrict__ gsum, const float* __restrict__ g,
                         const float* __restrict__ beta, const float* __restrict__ dinv,
                         unsigned* __restrict__ out) {
  __shared__ float Wl[64 * 48];
  __shared__ float Hl[16][64];
  __shared__ float scl[64], sft[64];
  int tid = threadIdx.x;
  int row0 = blockIdx.x * 16;
  if (tid < 64) {  // inline bn_finalize layer 1 (32 buckets)
    float s = 0.f, q = 0.f;
    for (int b = 0; b < 32; b++) {
      s += gsum[b * 128 + tid];
      q += gsum[b * 128 + 64 + tid];
    }
    float mean = s * INVN;
    float var = fmaxf(q * INVN - mean * mean, 0.f);
    float inv = rsqrtf(var + BN_EPS_F);
    float sc = g[tid] * inv;
    scl[tid] = sc;
    sft[tid] = beta[tid] - mean * sc;
  }
  for (int i = tid; i < 64 * 48; i += 256) Wl[i] = W[i];
  __syncthreads();
  for (int i = tid; i < 16 * 32; i += 256) {
    int r = i >> 5, j = i & 31;
    unsigned u = hu[(size_t)(row0 + r) * 32 + j];
    Hl[r][2 * j] = fmaxf(fmaf(bf_lo(u), scl[2 * j], sft[2 * j]), 0.f);
    Hl[r][2 * j + 1] = fmaxf(fmaf(bf_hi(u), scl[2 * j + 1], sft[2 * j + 1]), 0.f);
  }
  __syncthreads();
  int r = tid >> 4, c = tid & 15;
  if (c < 12) {
    float a0 = 0.f, a1 = 0.f, a2 = 0.f, a3 = 0.f;
#pragma unroll
    for (int k = 0; k < 64; k++) {
      float a = Hl[r][k];
      const float* w = &Wl[k * 48 + 4 * c];
      a0 = fmaf(a, w[0], a0);
      a1 = fmaf(a, w[1], a1);
      a2 = fmaf(a, w[2], a2);
      a3 = fmaf(a, w[3], a3);
    }
    float dd = dinv[row0 + r];
    uint2 uo = make_uint2(pack_bf2(dd * a0, dd * a1), pack_bf2(dd * a2, dd * a3));
    *(uint2*)(out + (size_t)(row0 + r) * 24 + 2 * c) = uo;
  }
}

// ---------------- layer-2 aggregate: bf16 rows of 24 uints (96B) -> bf16 h2 (24u), BN2 stats ----------------
// R10 loop shape, 32 stat buckets.

__launch_bounds__(256)
__global__ void aggregate_bf48(const uint2* __restrict__ mb, const int* __restrict__ rowptr,
                               const int* __restrict__ csr_src, const float* __restrict__ dinv,
                               const float* __restrict__ bias, unsigned* __restrict__ out,
                               float* __restrict__ gsum) {
  __shared__ float4 sbuf[256];  // 4 KB, two-phase
  int tid = threadIdx.x;
  int sub = tid >> 4, lane = tid & 15;
  int cl = (lane < 12) ? lane : lane - 12;
  int d = blockIdx.x * 16 + sub;
  int start = rowptr[d], end = rowptr[d + 1];
  uint2 su = mb[(size_t)d * 12 + cl];
  float acc0 = bf_lo(su.x), acc1 = bf_hi(su.x), acc2 = bf_lo(su.y), acc3 = bf_hi(su.y);
  int j = start;
  int aligned = (start + 3) & ~3;
  int pe = aligned < end ? aligned : end;
  for (; j < pe; j++) {
    uint2 u = mb[(size_t)csr_src[j] * 12 + cl];
    acc0 += bf_lo(u.x); acc1 += bf_hi(u.x); acc2 += bf_lo(u.y); acc3 += bf_hi(u.y);
  }
  for (; j + 16 <= end; j += 16) {
    int4 s0 = *(const int4*)(csr_src + j);
    int4 s1 = *(const int4*)(csr_src + j + 4);
    int4 s2 = *(const int4*)(csr_src + j + 8);
    int4 s3 = *(const int4*)(csr_src + j + 12);
    int idx[16] = {s0.x, s0.y, s0.z, s0.w, s1.x, s1.y, s1.z, s1.w,
                   s2.x, s2.y, s2.z, s2.w, s3.x, s3.y, s3.z, s3.w};
    uint2 u[16];
#pragma unroll
    for (int t = 0; t < 16; t++) u[t] = mb[(size_t)idx[t] * 12 + cl];
#pragma unroll
    for (int t = 0; t < 16; t++) {
      acc0 += bf_lo(u[t].x); acc1 += bf_hi(u[t].x);
      acc2 += bf_lo(u[t].y); acc3 += bf_hi(u[t].y);
    }
  }
  for (; j + 4 <= end; j += 4) {
    int4 s0 = *(const int4*)(csr_src + j);
    uint2 u0 = mb[(size_t)s0.x * 12 + cl], u1 = mb[(size_t)s0.y * 12 + cl];
    uint2 u2 = mb[(size_t)s0.z * 12 + cl], u3 = mb[(size_t)s0.w * 12 + cl];
    acc0 += bf_lo(u0.x) + bf_lo(u1.x) + bf_lo(u2.x) + bf_lo(u3.x);
    acc1 += bf_hi(u0.x) + bf_hi(u1.x) + bf_hi(u2.x) + bf_hi(u3.x);
    acc2 += bf_lo(u0.y) + bf_lo(u1.y) + bf_lo(u2.y) + bf_lo(u3.y);
    acc3 += bf_hi(u0.y) + bf_hi(u1.y) + bf_hi(u2.y) + bf_hi(u3.y);
  }
  for (; j < end; j++) {
    uint2 u = mb[(size_t)csr_src[j] * 12 + cl];
    acc0 += bf_lo(u.x); acc1 += bf_hi(u.x); acc2 += bf_lo(u.y); acc3 += bf_hi(u.y);
  }
  float dd = dinv[d];
  float v0 = dd * acc0 + bias[4 * cl];
  float v1 = dd * acc1 + bias[4 * cl + 1];
  float v2 = dd * acc2 + bias[4 * cl + 2];
  float v3 = dd * acc3 + bias[4 * cl + 3];
  if (lane >= 12) { v0 = v1 = v2 = v3 = 0.f; }
  if (lane < 12) {
    uint2 uo = make_uint2(pack_bf2(v0, v1), pack_bf2(v2, v3));
    *(uint2*)(out + (size_t)d * 24 + 2 * cl) = uo;
  }
  sbuf[tid] = make_float4(v0, v1, v2, v3);
  __syncthreads();
  float* gs = gsum + (blockIdx.x & 31) * 128;
  if (tid < 12) {
    float s0 = 0.f, s1 = 0.f, s2 = 0.f, s3 = 0.f;
#pragma unroll
    for (int k = 0; k < 16; k++) {
      float4 a = sbuf[k * 16 + tid];
      s0 += a.x; s1 += a.y; s2 += a.z; s3 += a.w;
    }
    atomicAdd(&gs[4 * tid], s0);
    atomicAdd(&gs[4 * tid + 1], s1);
    atomicAdd(&gs[4 * tid + 2], s2);
    atomicAdd(&gs[4 * tid + 3], s3);
  }
  __syncthreads();
  sbuf[tid] = make_float4(v0 * v0, v1 * v1, v2 * v2, v3 * v3);
  __syncthreads();
  if (tid < 12) {
    float q0 = 0.f, q1 = 0.f, q2 = 0.f, q3 = 0.f;
#pragma unroll
    for (int k = 0; k < 16; k++) {
      float4 b = sbuf[k * 16 + tid];
      q0 += b.x; q1 += b.y; q2 += b.z; q3 += b.w;
    }
    atomicAdd(&gs[64 + 4 * tid], q0);
    atomicAdd(&gs[64 + 4 * tid + 1], q1);
    atomicAdd(&gs[64 + 4 * tid + 2], q2);
    atomicAdd(&gs[64 + 4 * tid + 3], q3);
  }
}

// ---------------- layer-3 GEMM (inline BN2 finalize): h2 bf16 24u -> m3b bf16 16u pre-scaled ----------------

__launch_bounds__(256)
__global__ void gemm3_bf(const unsigned* __restrict__ hu, const float* __restrict__ W,
                         const float* __restrict__ gsum, const float* __restrict__ g,
                         const float* __restrict__ beta, const float* __restrict__ dinv,
                         unsigned* __restrict__ out) {
  __shared__ float Wl[48 * 32];
  __shared__ float Hl[16][48];
  __shared__ float scl[48], sft[48];
  int tid = threadIdx.x;
  int row0 = blockIdx.x * 16;
  if (tid < 48) {  // inline bn_finalize layer 2 (32 buckets)
    float s = 0.f, q = 0.f;
    for (int b = 0; b < 32; b++) {
      s += gsum[b * 128 + tid];
      q += gsum[b * 128 + 64 + tid];
    }
    float mean = s * INVN;
    float var = fmaxf(q * INVN - mean * mean, 0.f);
    float inv = rsqrtf(var + BN_EPS_F);
    float sc = g[tid] * inv;
    scl[tid] = sc;
    sft[tid] = beta[tid] - mean * sc;
  }
  for (int i = tid; i < 48 * 32; i += 256) Wl[i] = W[i];
  __syncthreads();
  for (int i = tid; i < 16 * 24; i += 256) {
    int r = i / 24, j = i % 24;
    unsigned u = hu[(size_t)(row0 + r) * 24 + j];
    Hl[r][2 * j] = fmaxf(fmaf(bf_lo(u), scl[2 * j], sft[2 * j]), 0.f);
    Hl[r][2 * j + 1] = fmaxf(fmaf(bf_hi(u), scl[2 * j + 1], sft[2 * j + 1]), 0.f);
  }
  __syncthreads();
  int r = tid >> 4, c2 = tid & 15;
  float a0 = 0.f, a1 = 0.f;
#pragma unroll
  for (int k = 0; k < 48; k++) {
    float a = Hl[r][k];
    a0 = fmaf(a, Wl[k * 32 + 2 * c2], a0);
    a1 = fmaf(a, Wl[k * 32 + 2 * c2 + 1], a1);
  }
  float dd = dinv[row0 + r];
  out[(size_t)(row0 + r) * 16 + c2] = pack_bf2(dd * a0, dd * a1);
}

// ---------------- layer-3 aggregate: bf16 rows 16u -> bf16 h3 16u, BN3 stats ----------------
// R10 loop shape, 32 stat buckets.

__launch_bounds__(256)
__global__ void aggregate_bf32(const unsigned* __restrict__ mb, const int* __restrict__ rowptr,
                               const int* __restrict__ csr_src, const float* __restrict__ dinv,
                               const float* __restrict__ bias, unsigned* __restrict__ out,
                               float* __restrict__ gsum) {
  __shared__ float2 ssum[256], ssq[256];
  int tid = threadIdx.x;
  int sub = tid >> 4, lane = tid & 15;
  int d = blockIdx.x * 16 + sub;
  int start = rowptr[d], end = rowptr[d + 1];
  unsigned su = mb[(size_t)d * 16 + lane];
  float acc0 = bf_lo(su), acc1 = bf_hi(su);
  int j = start;
  int aligned = (start + 3) & ~3;
  int pe = aligned < end ? aligned : end;
  for (; j < pe; j++) {
    unsigned u = mb[(size_t)csr_src[j] * 16 + lane];
    acc0 += bf_lo(u); acc1 += bf_hi(u);
  }
  for (; j + 16 <= end; j += 16) {
    int4 s0 = *(const int4*)(csr_src + j);
    int4 s1 = *(const int4*)(csr_src + j + 4);
    int4 s2 = *(const int4*)(csr_src + j + 8);
    int4 s3 = *(const int4*)(csr_src + j + 12);
    int idx[16] = {s0.x, s0.y, s0.z, s0.w, s1.x, s1.y, s1.z, s1.w,
                   s2.x, s2.y, s2.z, s2.w, s3.x, s3.y, s3.z, s3.w};
    unsigned u[16];
#pragma unroll
    for (int t = 0; t < 16; t++) u[t] = mb[(size_t)idx[t] * 16 + lane];
#pragma unroll
    for (int t = 0; t < 16; t++) { acc0 += bf_lo(u[t]); acc1 += bf_hi(u[t]); }
  }
  for (; j + 4 <= end; j += 4) {
    int4 s0 = *(const int4*)(csr_src + j);
    unsigned u0 = mb[(size_t)s0.x * 16 + lane], u1 = mb[(size_t)s0.y * 16 + lane];
    unsigned u2 = mb[(size_t)s0.z * 16 + lane], u3 = mb[(size_t)s0.w * 16 + lane];
    acc0 += bf_lo(u0) + bf_lo(u1) + bf_lo(u2) + bf_lo(u3);
    acc1 += bf_hi(u0) + bf_hi(u1) + bf_hi(u2) + bf_hi(u3);
  }
  for (; j < end; j++) {
    unsigned u = mb[(size_t)csr_src[j] * 16 + lane];
    acc0 += bf_lo(u); acc1 += bf_hi(u);
  }
  float dd = dinv[d];
  float v0 = dd * acc0 + bias[2 * lane];
  float v1 = dd * acc1 + bias[2 * lane + 1];
  out[(size_t)d * 16 + lane] = pack_bf2(v0, v1);
  ssum[tid] = make_float2(v0, v1);
  ssq[tid] = make_float2(v0 * v0, v1 * v1);
  __syncthreads();
  if (tid < 16) {
    float s0 = 0.f, s1 = 0.f, q0 = 0.f, q1 = 0.f;
#pragma unroll
    for (int k = 0; k < 16; k++) {
      float2 a = ssum[k * 16 + tid];
      float2 b = ssq[k * 16 + tid];
      s0 += a.x; s1 += a.y; q0 += b.x; q1 += b.y;
    }
    float* gs = gsum + (blockIdx.x & 31) * 128;
    atomicAdd(&gs[2 * tid], s0);
    atomicAdd(&gs[2 * tid + 1], s1);
    atomicAdd(&gs[64 + 2 * tid], q0);
    atomicAdd(&gs[64 + 2 * tid + 1], q1);
  }
}

// ---------------- BN3 finalize (inline) + apply: bf16 h3 -> fp32 out ----------------

__launch_bounds__(256)
__global__ void bn_apply_out(const unsigned* __restrict__ hu, const float* __restrict__ gsum,
                             const float* __restrict__ g, const float* __restrict__ beta,
                             float* __restrict__ out) {
  __shared__ float scl[32], sft[32];
  int tid = threadIdx.x;
  if (tid < 32) {  // inline bn_finalize layer 3 (32 buckets)
    float s = 0.f, q = 0.f;
    for (int b = 0; b < 32; b++) {
      s += gsum[b * 128 + tid];
      q += gsum[b * 128 + 64 + tid];
    }
    float mean = s * INVN;
    float var = fmaxf(q * INVN - mean * mean, 0.f);
    float inv = rsqrtf(var + BN_EPS_F);
    float sc = g[tid] * inv;
    scl[tid] = sc;
    sft[tid] = beta[tid] - mean * sc;
  }
  __syncthreads();
  int base = (blockIdx.x * 256 + tid) * 4;  // 4 consecutive elems, same node
  int node = base >> 5;
  int c0 = base & 31;
  uint2 u = *(const uint2*)(hu + (size_t)node * 16 + (c0 >> 1));
  float4 o;
  o.x = bf_lo(u.x) * scl[c0] + sft[c0];
  o.y = bf_hi(u.x) * scl[c0 + 1] + sft[c0 + 1];
  o.z = bf_lo(u.y) * scl[c0 + 2] + sft[c0 + 2];
  o.w = bf_hi(u.y) * scl[c0 + 3] + sft[c0 + 3];
  *(float4*)(out + base) = o;
}

// ---------------- launch ----------------

extern "C" void kernel_launch(void* const* d_in, const int* in_sizes, int n_in,
                              void* d_out, int out_size, void* d_ws, size_t ws_size,
                              hipStream_t stream) {
  const float* x = (const float*)d_in[0];
  const int* ei = (const int*)d_in[1];
  const float* W1 = (const float*)d_in[2];
  const float* b1 = (const float*)d_in[3];
  const float* g1 = (const float*)d_in[4];
  const float* be1 = (const float*)d_in[5];
  const float* W2 = (const float*)d_in[6];
  const float* b2 = (const float*)d_in[7];
  const float* g2 = (const float*)d_in[8];
  const float* be2 = (const float*)d_in[9];
  const float* W3 = (const float*)d_in[10];
  const float* b3 = (const float*)d_in[11];
  const float* g3 = (const float*)d_in[12];
  const float* be3 = (const float*)d_in[13];
  float* out = (float*)d_out;

  const int* src = ei;
  const int* dst = ei + NE;

  char* ws = (char*)d_ws;
  size_t off = 0;
  auto alloc = [&](size_t bytes) -> void* {
    void* p = ws + off;
    off += bytes;
    off = (off + 255) & ~(size_t)255;
    return p;
  };
  int* ph = (int*)alloc((size_t)MTOT * 4);
  int* bsums = (int*)alloc(128 * 4);
  int* packed = (int*)alloc((size_t)NE * 4);
  int* rowptr = (int*)alloc((NN + 1) * 4);
  int* csr_src = (int*)alloc((size_t)NE * 4);
  float* dinv = (float*)alloc(NN * 4);
  float* gsum = (float*)alloc(3 * 32 * 128 * 4);  // 32 buckets per layer
  unsigned* xb = (unsigned*)alloc((size_t)NN * 16 * 4);   // 6.4 MB (reused: m3b)
  unsigned* h1u = (unsigned*)alloc((size_t)NN * 32 * 4);  // 12.8 MB (reused: h3)
  unsigned* m2b = (unsigned*)alloc((size_t)NN * 24 * 4);  // 9.6 MB
  unsigned* h2u = (unsigned*)alloc((size_t)NN * 24 * 4);  // 9.6 MB

  unsigned* m3b = xb;   // xb dead after agg1_gemm1
  unsigned* h3u = h1u;  // h1 dead after gemm2

  hipMemsetAsync(gsum, 0, 3 * 32 * 128 * 4, stream);

  const int nscan = (MTOT + SCH - 1) / SCH;  // 75
  hist_pass<<<NEB, 256, 0, stream>>>(dst, ph, NE);
  scan_block_sums<<<nscan, 256, 0, stream>>>(ph, bsums, MTOT);
  scan_bsums2<<<1, 128, 0, stream>>>(bsums, nscan);
  scan_apply<<<nscan, 256, 0, stream>>>(ph, bsums, MTOT);
  bin_pass<<<NEB, 256, 0, stream>>>(src, dst, ph, packed, NE);
  bucket_finalize<<<NBKT, 256, 0, stream>>>(ph, packed, x, rowptr, dinv, csr_src, xb);

  // layer 1: fused aggregate(x) + GEMM1 + BN1 stats
  agg1_gemm1<<<NN / 16, 256, 0, stream>>>(xb, rowptr, csr_src, dinv, W1, b1, h1u, gsum);

  // layer 2: GEMM2 (inline BN1 finalize) -> aggregate (BN2 stats)
  gemm2_bf<<<NN / 16, 256, 0, stream>>>(h1u, W2, gsum, g1, be1, dinv, m2b);
  aggregate_bf48<<<NN / 16, 256, 0, stream>>>((const uint2*)m2b, rowptr, csr_src, dinv, b2, h2u,
                                              gsum + 4096);

  // layer 3: GEMM3 (inline BN2 finalize) -> aggregate (BN3 stats)
  gemm3_bf<<<NN / 16, 256, 0, stream>>>(h2u, W3, gsum + 4096, g2, be2, dinv, m3b);
  aggregate_bf32<<<NN / 16, 256, 0, stream>>>(m3b, rowptr, csr_src, dinv, b3, h3u, gsum + 8192);

  // BN3 finalize (inline) + apply
  bn_apply_out<<<NN * 32 / 1024, 256, 0, stream>>>(h3u, gsum + 8192, g3, be3, out);
}